// Round 1
// 28.527 us; speedup vs baseline: 1.0624x; 1.0624x over previous
//
#include <hip/hip_runtime.h>
#include <math.h>

// GBST forward. B=8, L=2048, D=256, NGRAM=4. R12 = R11 with:
//  - 3-deep slab pipeline (48 VGPR) + __launch_bounds__(256,4): 4 blocks/CU
//    (R11 was 4-deep/64 VGPR -> 170 cap -> 3 blocks/CU; latency-bound regime
//    wants TLP more than the extra pipeline stage).
//  - block-uniform tokens in SGPRs (readfirstlane, compile-time indices only;
//    conv branches on wave-uniform half) + 24-bit validity mask. Removes the
//    seq->LDS->ds_read chain and the sseq[] LDS array.
//  - conv gathers emb as f32 float2 directly; x16 (sqrt D) folded into taps.
//    k_prep no longer builds the bf16 emb table.
//  - __expf in wts phase.
// Math otherwise identical to R11 (passing, absmax 7.8e-3).

#define D_ 256
#define M_ 24                 // positions per block (multiple of 12)
#define BPB 86                // ceil(2048/24)
#define LSTR 264              // ushort stride: 528B, 16B-aligned

typedef __attribute__((ext_vector_type(8))) short bf16x8;
typedef __attribute__((ext_vector_type(4))) float f32x4;

__device__ __forceinline__ ushort f2bf(float f) {
    union { float f; unsigned u; } v; v.f = f;
    unsigned r = v.u + 0x7fffu + ((v.u >> 16) & 1u);   // RNE
    return (ushort)(r >> 16);
}
__device__ __forceinline__ float bf2f(ushort h) {
    union { unsigned u; float f; } v; v.u = ((unsigned)h) << 16;
    return v.f;
}

// load one k8-slab (4 B-frags for this wave's n-quarter)
#define LDB4(v0, v1, v2, v3, W, K8) do { \
    const ushort* bp_ = (W) + ((size_t)((K8) * 16 + w * 4) * 64 + ln) * 8; \
    v0 = *(const bf16x8*)(bp_); \
    v1 = *(const bf16x8*)(bp_ + 512); \
    v2 = *(const bf16x8*)(bp_ + 1024); \
    v3 = *(const bf16x8*)(bp_ + 1536); \
} while (0)

// 8 MFMAs for one k8: 4 n-tiles x 2 m-stripes
#define MFMA8(ACC, K8, v0, v1, v2, v3) do { \
    bf16x8 a0_ = *(const bf16x8*)&x_lds[lr][(K8) * 32 + koff]; \
    bf16x8 a1_ = *(const bf16x8*)&x_lds[16 + lr][(K8) * 32 + koff]; \
    ACC[0][0] = __builtin_amdgcn_mfma_f32_16x16x32_bf16(a0_, v0, ACC[0][0], 0, 0, 0); \
    ACC[1][0] = __builtin_amdgcn_mfma_f32_16x16x32_bf16(a1_, v0, ACC[1][0], 0, 0, 0); \
    ACC[0][1] = __builtin_amdgcn_mfma_f32_16x16x32_bf16(a0_, v1, ACC[0][1], 0, 0, 0); \
    ACC[1][1] = __builtin_amdgcn_mfma_f32_16x16x32_bf16(a1_, v1, ACC[1][1], 0, 0, 0); \
    ACC[0][2] = __builtin_amdgcn_mfma_f32_16x16x32_bf16(a0_, v2, ACC[0][2], 0, 0, 0); \
    ACC[1][2] = __builtin_amdgcn_mfma_f32_16x16x32_bf16(a1_, v2, ACC[1][2], 0, 0, 0); \
    ACC[0][3] = __builtin_amdgcn_mfma_f32_16x16x32_bf16(a0_, v3, ACC[0][3], 0, 0, 0); \
    ACC[1][3] = __builtin_amdgcn_mfma_f32_16x16x32_bf16(a1_, v3, ACC[1][3], 0, 0, 0); \
} while (0)

#define SBAR __builtin_amdgcn_sched_barrier(0)

// ---------------------------------------------------------------------------
// K0: proj_w/ff_w -> bf16 FRAGMENT-MAJOR:
// wq[((k8*16+nb)*64+ln)*8+j] = w[(nb*16+(ln&15))*256 + k8*32+(ln>>4)*8+j]
// ---------------------------------------------------------------------------
__global__ __launch_bounds__(256) void k_prep(
    const float* __restrict__ pw, const float* __restrict__ fw,
    ushort* __restrict__ wqp, ushort* __restrict__ wqf)
{
    int i = blockIdx.x * 256 + threadIdx.x;   // 0..65535
    int j  = i & 7;
    int ln = (i >> 3) & 63;
    int nb = (i >> 9) & 15;
    int k8 = i >> 13;
    int er = nb * 16 + (ln & 15);
    int k  = k8 * 32 + (ln >> 4) * 8 + j;
    wqp[i] = f2bf(pw[er * D_ + k]);
    wqf[i] = f2bf(fw[er * D_ + k]);
}

// ---------------------------------------------------------------------------
// K1: 256 threads / 4 waves, M=24 positions, 3 barriers, 3-deep GEMM pipes.
// ---------------------------------------------------------------------------
__global__ __launch_bounds__(256, 4) void k_main(
    const int* __restrict__ seq, const float* __restrict__ emb,
    const float* __restrict__ conv_w, const float* __restrict__ conv_b,
    const ushort* __restrict__ wqp, const float* __restrict__ proj_b,
    const float* __restrict__ score_w,
    const ushort* __restrict__ wqf, const float* __restrict__ ff_b,
    float* __restrict__ out, int L)
{
    __shared__ ushort x_lds[32][LSTR];   // conv x (A proj) -> o (A FF); 24..31 zero
    __shared__ ushort x2[M_][LSTR];      // masked x (mix input)
    __shared__ float xsred[4][M_];
    __shared__ float wts[4][12][4];      // per-wave copy; tile = w>>1
    const int b  = blockIdx.x / BPB;
    const int l0 = (blockIdx.x % BPB) * M_;   // 24 | l0
    const int t  = threadIdx.x;
    const int w  = t >> 6, ln = t & 63;
    const int lr = ln & 15, q = ln >> 4;
    const int koff = q * 8;

    // ---- block-uniform tokens in SGPRs (compile-time indices only) ----
    int tok[M_ + 3];
    {
        const int* seqp = seq + (size_t)b * L + l0;
        #pragma unroll
        for (int r = 0; r < M_ + 3; ++r) {
            int tv = -1;                       // OOB -> zero-pad embedding
            if (l0 + r < L) tv = __builtin_amdgcn_readfirstlane(seqp[r]);
            tok[r] = tv;
        }
    }
    unsigned vmask = 0;                        // bit row: seq > 0 (valid)
    #pragma unroll
    for (int r = 0; r < M_; ++r) vmask |= (tok[r] > 0) ? (1u << r) : 0u;

    // slab registers (shared by proj and FF pipelines), 3-deep
    bf16x8 s00, s01, s02, s03, s10, s11, s12, s13, s20, s21, s22, s23;
    // issue proj slabs 0..2 now (independent of conv)
    LDB4(s00, s01, s02, s03, wqp, 0);
    LDB4(s10, s11, s12, s13, wqp, 1);
    LDB4(s20, s21, s22, s23, wqp, 2);
    SBAR;

    // zero A rows 24..31 (8 rows x 512B = 256 thr x 16B)
    {
        int zr = 24 + (t >> 5), zc = (t & 31) * 8;
        *(uint4*)&x_lds[zr][zc] = make_uint4(0, 0, 0, 0);
    }

    // ---- conv: half h = t>>7 (== w>>1, wave-uniform) does rows h*12..h*12+11,
    //      channel pair; emb read as f32, x16 folded into taps ----
    {
        const int h = t >> 7;
        const int ch0 = (t & 127) * 2;
        float4 wa = *(const float4*)(conv_w + ch0 * 4);
        float4 wb = *(const float4*)(conv_w + ch0 * 4 + 4);
        wa.x *= 16.f; wa.y *= 16.f; wa.z *= 16.f; wa.w *= 16.f;
        wb.x *= 16.f; wb.y *= 16.f; wb.z *= 16.f; wb.w *= 16.f;
        const float cba = conv_b[ch0], cbb = conv_b[ch0 + 1];
        #define CONV_HALF(BASE) do { \
            float2 er[15]; \
            _Pragma("unroll") \
            for (int r = 0; r < 15; ++r) { \
                int sn = tok[(BASE) + r]; \
                float2 e; e.x = 0.f; e.y = 0.f; \
                if (sn >= 0) e = *(const float2*)(emb + (size_t)sn * D_ + ch0); \
                er[r] = e; \
            } \
            _Pragma("unroll") \
            for (int r = 0; r < 12; ++r) { \
                float cx = fmaf(wa.x, er[r].x, fmaf(wa.y, er[r+1].x, \
                           fmaf(wa.z, er[r+2].x, fmaf(wa.w, er[r+3].x, cba)))); \
                float cy = fmaf(wb.x, er[r].y, fmaf(wb.y, er[r+1].y, \
                           fmaf(wb.z, er[r+2].y, fmaf(wb.w, er[r+3].y, cbb)))); \
                *(unsigned*)&x_lds[(BASE) + r][ch0] = \
                    (unsigned)f2bf(cx) | ((unsigned)f2bf(cy) << 16); \
            } \
        } while (0)
        if (h == 0) { CONV_HALF(0); } else { CONV_HALF(12); }
        #undef CONV_HALF
    }
    __syncthreads();   // B0: conv done -> A readable

    // ---- proj GEMM: 3-slab-deep pipeline ----
    f32x4 acc[2][4];
    #pragma unroll
    for (int s = 0; s < 2; ++s)
        #pragma unroll
        for (int n = 0; n < 4; ++n) acc[s][n] = (f32x4){0.f, 0.f, 0.f, 0.f};
    MFMA8(acc, 0, s00, s01, s02, s03); LDB4(s00, s01, s02, s03, wqp, 3); SBAR;
    MFMA8(acc, 1, s10, s11, s12, s13); LDB4(s10, s11, s12, s13, wqp, 4); SBAR;
    MFMA8(acc, 2, s20, s21, s22, s23); LDB4(s20, s21, s22, s23, wqp, 5); SBAR;
    MFMA8(acc, 3, s00, s01, s02, s03); LDB4(s00, s01, s02, s03, wqp, 6); SBAR;
    MFMA8(acc, 4, s10, s11, s12, s13); LDB4(s10, s11, s12, s13, wqp, 7); SBAR;
    MFMA8(acc, 5, s20, s21, s22, s23);
    MFMA8(acc, 6, s00, s01, s02, s03);
    MFMA8(acc, 7, s10, s11, s12, s13);

    // ---- epilogue: mask+bias -> x2 rows 0..23 + xs partials ----
    {
        float xsp[8] = {0,0,0,0,0,0,0,0};   // [s*4+r]
        #pragma unroll
        for (int n = 0; n < 4; ++n) {
            int e = w * 64 + n * 16 + lr;
            float pb = proj_b[e], sw = score_w[e];
            #pragma unroll
            for (int s = 0; s < 2; ++s) {
                #pragma unroll
                for (int r = 0; r < 4; ++r) {
                    int row = s * 16 + q * 4 + r;
                    if (row < M_) {
                        float v = ((vmask >> row) & 1u) ? acc[s][n][r] + pb : 0.f;
                        x2[row][e] = f2bf(v);
                        xsp[s * 4 + r] = fmaf(v, sw, xsp[s * 4 + r]);
                    }
                }
            }
        }
        #pragma unroll
        for (int off = 1; off < 16; off <<= 1) {
            #pragma unroll
            for (int i = 0; i < 8; ++i) xsp[i] += __shfl_xor(xsp[i], off, 64);
        }
        if (lr == 0) {
            #pragma unroll
            for (int r = 0; r < 4; ++r) xsred[w][q * 4 + r] = xsp[r];
            if (q < 2) {
                #pragma unroll
                for (int r = 0; r < 4; ++r) xsred[w][16 + q * 4 + r] = xsp[4 + r];
            }
        }
    }
    __syncthreads();   // B1: x2 + xsred complete; x_lds A-reads all done

    // issue FF slabs 0..2 NOW -> latency hides under wts+mix VALU work
    LDB4(s00, s01, s02, s03, wqf, 0);
    LDB4(s10, s11, s12, s13, wqf, 1);
    LDB4(s20, s21, s22, s23, wqf, 2);
    SBAR;

    // ---- softmax weights (per-wave redundant; lanes 0..11; tile = w>>1) ----
    if (ln < 12) {
        const int p = (w >> 1) * 12 + ln;   // global row 0..23
        if (!((vmask >> p) & 1u)) {
            wts[w][ln][0] = wts[w][ln][1] = wts[w][ln][2] = wts[w][ln][3] = 0.f;
        } else {
            #define XS(i) (xsred[0][i] + xsred[1][i] + xsred[2][i] + xsred[3][i])
            float s0 = XS(p);
            int r2 = p & ~1;
            float c2 = (float)__popc((vmask >> r2) & 3u);    // >=1: p valid
            float m2 = (XS(r2) + XS(r2 + 1)) / c2;
            int r3 = p - (p % 3);
            float c3 = (float)__popc((vmask >> r3) & 7u);
            float m3 = (XS(r3) + XS(r3 + 1) + XS(r3 + 2)) / c3;
            int r4 = p & ~3;
            float c4 = (float)__popc((vmask >> r4) & 15u);
            float m4 = (XS(r4) + XS(r4 + 1) + XS(r4 + 2) + XS(r4 + 3)) / c4;
            float mx = fmaxf(fmaxf(s0, m2), fmaxf(m3, m4));
            float q0 = __expf(s0 - mx), q2 = __expf(m2 - mx);
            float q3 = __expf(m3 - mx), q4 = __expf(m4 - mx);
            float iZ = 1.f / (q0 + 2.f * q2 + 3.f * q3 + 4.f * q4);
            wts[w][ln][0] = q0 * iZ;
            wts[w][ln][1] = 2.f * q2 * iZ / c2;   // inv counts folded
            wts[w][ln][2] = 3.f * q3 * iZ / c3;
            wts[w][ln][3] = 4.f * q4 * iZ / c4;
            #undef XS
        }
    }
    asm volatile("s_waitcnt lgkmcnt(0)" ::: "memory");
    SBAR;

    // ---- mix: tile = t>>7 (= w>>1), channel pair; o -> x_lds rows 0..23 ----
    {
        const int tile = t >> 7;
        const int r0 = tile * 12;
        const int ch0 = (t & 127) * 2;
        float2 xr[12];
        #pragma unroll
        for (int p = 0; p < 12; ++p) {
            unsigned v = *(const unsigned*)&x2[r0 + p][ch0];
            xr[p].x = bf2f((ushort)(v & 0xffff));
            xr[p].y = bf2f((ushort)(v >> 16));
        }
        float s2x[6], s2y[6], s3x[4], s3y[4], s4x[3], s4y[3];
        #pragma unroll
        for (int j = 0; j < 6; ++j) {
            s2x[j] = xr[2*j].x + xr[2*j+1].x;
            s2y[j] = xr[2*j].y + xr[2*j+1].y;
        }
        #pragma unroll
        for (int j = 0; j < 4; ++j) {
            s3x[j] = xr[3*j].x + xr[3*j+1].x + xr[3*j+2].x;
            s3y[j] = xr[3*j].y + xr[3*j+1].y + xr[3*j+2].y;
        }
        #pragma unroll
        for (int j = 0; j < 3; ++j) {
            s4x[j] = xr[4*j].x + xr[4*j+1].x + xr[4*j+2].x + xr[4*j+3].x;
            s4y[j] = xr[4*j].y + xr[4*j+1].y + xr[4*j+2].y + xr[4*j+3].y;
        }
        #pragma unroll
        for (int p = 0; p < 12; ++p) {
            float4 wv = *(const float4*)&wts[w][p][0];
            float ox = wv.x*xr[p].x + wv.y*s2x[p>>1] + wv.z*s3x[p/3] + wv.w*s4x[p>>2];
            float oy = wv.x*xr[p].y + wv.y*s2y[p>>1] + wv.z*s3y[p/3] + wv.w*s4y[p>>2];
            *(unsigned*)&x_lds[r0 + p][ch0] =
                (unsigned)f2bf(ox) | ((unsigned)f2bf(oy) << 16);
        }
    }
    __syncthreads();   // B2: o rows 0..23 done (24..31 stay zero)

    // ---- FF GEMM: 3-slab-deep pipeline (slabs 0..2 already in flight) ----
    f32x4 ffa[2][4];
    #pragma unroll
    for (int s = 0; s < 2; ++s)
        #pragma unroll
        for (int n = 0; n < 4; ++n) ffa[s][n] = (f32x4){0.f, 0.f, 0.f, 0.f};
    MFMA8(ffa, 0, s00, s01, s02, s03); LDB4(s00, s01, s02, s03, wqf, 3); SBAR;
    MFMA8(ffa, 1, s10, s11, s12, s13); LDB4(s10, s11, s12, s13, wqf, 4); SBAR;
    MFMA8(ffa, 2, s20, s21, s22, s23); LDB4(s20, s21, s22, s23, wqf, 5); SBAR;
    MFMA8(ffa, 3, s00, s01, s02, s03); LDB4(s00, s01, s02, s03, wqf, 6); SBAR;
    MFMA8(ffa, 4, s10, s11, s12, s13); LDB4(s10, s11, s12, s13, wqf, 7); SBAR;
    MFMA8(ffa, 5, s20, s21, s22, s23);
    MFMA8(ffa, 6, s00, s01, s02, s03);
    MFMA8(ffa, 7, s10, s11, s12, s13);

    // ---- store out = o + relu(ff + fb), rows 0..23, l < L ----
    #pragma unroll
    for (int n = 0; n < 4; ++n) {
        int e = w * 64 + n * 16 + lr;
        float fb = ff_b[e];
        #pragma unroll
        for (int s = 0; s < 2; ++s) {
            #pragma unroll
            for (int r = 0; r < 4; ++r) {
                int row = s * 16 + q * 4 + r;
                if (row < M_) {
                    int l = l0 + row;
                    if (l < L) {
                        float o = bf2f(x_lds[row][e]);
                        out[((size_t)b * L + l) * D_ + e]
                            = o + fmaxf(ffa[s][n][r] + fb, 0.f);
                    }
                }
            }
        }
    }
}

// ---------------------------------------------------------------------------
extern "C" void kernel_launch(void* const* d_in, const int* in_sizes, int n_in,
                              void* d_out, int out_size, void* d_ws, size_t ws_size,
                              hipStream_t stream) {
    const int*   seq     = (const int*)d_in[0];
    // d_in[1] = group_id : redundant (groups are pos//s, validity = seq!=0)
    const float* emb     = (const float*)d_in[2];
    const float* conv_w  = (const float*)d_in[3];
    const float* conv_b  = (const float*)d_in[4];
    const float* proj_w  = (const float*)d_in[5];
    const float* proj_b  = (const float*)d_in[6];
    const float* score_w = (const float*)d_in[7];
    // d_in[8] = score_b : constant shift, cancels in softmax
    const float* ff_w    = (const float*)d_in[9];
    const float* ff_b    = (const float*)d_in[10];
    float* out = (float*)d_out;

    const int L = 2048;
    const int B = in_sizes[0] / L;

    ushort* wqp = (ushort*)d_ws;          // [65536] bf16 fragment-major
    ushort* wqf = wqp + D_ * D_;          // [65536] bf16 fragment-major

    k_prep<<<D_ * D_ / 256, 256, 0, stream>>>(proj_w, ff_w, wqp, wqf);
    k_main<<<B * BPB, 256, 0, stream>>>(seq, emb, conv_w, conv_b, wqp, proj_b,
                                        score_w, wqf, ff_b, out, L);
}